// Round 2
// 1466.883 us; speedup vs baseline: 1.4635x; 1.4635x over previous
//
#include <hip/hip_runtime.h>
#include <hip/hip_bf16.h>

// ---------------------------------------------------------------------------
// VariLengthInputLayer on MI355X (gfx950)
// bs=16384, DIMS={2048,1024,512,1536,768,256} (sum 6144), NH=8, DK=DV=64, dm=512
//
// Math note: attn/|attn.min()| followed by row-L2-normalize cancels the global
// min exactly (norm(a/c)=norm(a)/c), so no device-wide reduction is needed.
//
// v3 structure (v2 crashed: peak ws use 523 MB > proven 321 MB budget):
//   Batch processed in 2 halves of 8192 rows — the whole post-proj pipeline is
//   per-row, so only half-sized A16/Q/K/V buffers are ever live. Peak ws use
//   271,057,152 B < 321,388,800 B (the footprint the harness already accepted).
//   A16h (100 MB) is L3-resident -> GEMM A-reads hit Infinity Cache.
//
//   k_cvtA  : input half -> packed fp16 A16h (once per half)
//   k_gemm  : m97-style 128x128x64, global_load_lds(16B), QKV fused (N=1536
//             per segment, weights contiguous), bijective XCD-chunk swizzle
//   k_att   : all LDS traffic b128-vectorized; XOR swizzle on byte bits[4:6]
//             kills the 128B-stride same-bank pileup
//   k_epi   : half8 loads / uint4-float4 stores
//
// Workspace layout (bytes), per half (buffers reused across halves):
//   [0,256)                    flag
//   [256, 19398912)            Wh: 18 proj weights + fc_w as fp16
//   [19398912, 120062208)      A16h fp16 (8192 x 6144)   -- reused as Oh
//   [120062208, 170393856)     Qh fp16 (8192*3072)       -- reused as Yh
//   [170393856, 220725504)     Kh fp16
//   [220725504, 271057152)     Vh fp16
// Aliases safe: kernels are stream-serial; A16h dead after proj GEMM of its
// half, Qh dead after k_att of its half.
// ---------------------------------------------------------------------------

typedef _Float16 half8 __attribute__((ext_vector_type(8)));
typedef float floatx4 __attribute__((ext_vector_type(4)));

#define NSEG 6
#define LDA 6144
#define BS_TOT 16384
#define BS_HALF 8192
#define OUT0_ELEMS 50331648L  // 16384*6*512

__device__ __forceinline__ float bf_to_f(unsigned short u) {
  unsigned int w = ((unsigned int)u) << 16;
  return __uint_as_float(w);
}
__device__ __forceinline__ unsigned short f_to_bf(float f) {
  unsigned int u = __float_as_uint(f);
  u = (u + 0x7fffu + ((u >> 16) & 1u)) >> 16;  // RTNE
  return (unsigned short)u;
}
__device__ __forceinline__ float ld_any(const void* p, long i, int isbf) {
  return isbf ? bf_to_f(((const unsigned short*)p)[i]) : ((const float*)p)[i];
}
__device__ __forceinline__ void st_any(void* p, long i, float v, int isbf) {
  if (isbf) ((unsigned short*)p)[i] = f_to_bf(v);
  else      ((float*)p)[i] = v;
}

// ---------------- dtype detection ----------------
__global__ void k_detect(const unsigned short* x, int* flag) {
  __shared__ float sm[256];
  float m = 0.f;
  for (int i = threadIdx.x; i < 512; i += 256) {
    float v = fabsf(bf_to_f(x[i]));
    if (!(v < 1e30f)) v = 1e30f;
    m = fmaxf(m, v);
  }
  sm[threadIdx.x] = m;
  __syncthreads();
  for (int s = 128; s > 0; s >>= 1) {
    if (threadIdx.x < s) sm[threadIdx.x] = fmaxf(sm[threadIdx.x], sm[threadIdx.x + s]);
    __syncthreads();
  }
  if (threadIdx.x == 0) flag[0] = (sm[0] > 1e3f) ? 0 : 1;  // 0=fp32, 1=bf16
}

// ---------------- weights -> fp16 ----------------
struct PrepArgs {
  const void* src[19];
  int cs[20];
};
__global__ void k_prep(PrepArgs pa, _Float16* wh, const int* flag, int total) {
  int idx = blockIdx.x * 256 + threadIdx.x;
  if (idx >= total) return;
  int isbf = flag[0];
  int a = 0;
  while (pa.cs[a + 1] <= idx) ++a;
  wh[idx] = (_Float16)ld_any(pa.src[a], idx - pa.cs[a], isbf);
}

// ---------------- input half -> packed fp16 ----------------
__global__ void k_cvtA(const void* src, _Float16* dst, const int* flag,
                       long elem0, long nchunk) {
  const int isbf = flag[0];
  long i = (long)blockIdx.x * 256 + threadIdx.x;
  const long stride = (long)gridDim.x * 256;
  for (; i < nchunk; i += stride) {
    half8 h;
    if (isbf) {
      uint4 r = ((const uint4*)src)[elem0 / 8 + i];
      unsigned int wb[4] = {r.x, r.y, r.z, r.w};
      for (int t = 0; t < 4; ++t) {
        h[2 * t]     = (_Float16)__uint_as_float(wb[t] << 16);
        h[2 * t + 1] = (_Float16)__uint_as_float(wb[t] & 0xffff0000u);
      }
    } else {
      float4 f0 = ((const float4*)src)[elem0 / 4 + 2 * i];
      float4 f1 = ((const float4*)src)[elem0 / 4 + 2 * i + 1];
      h[0] = (_Float16)f0.x; h[1] = (_Float16)f0.y;
      h[2] = (_Float16)f0.z; h[3] = (_Float16)f0.w;
      h[4] = (_Float16)f1.x; h[5] = (_Float16)f1.y;
      h[6] = (_Float16)f1.z; h[7] = (_Float16)f1.w;
    }
    ((half8*)dst)[i] = h;
  }
}

// ---------------- fp16 MFMA GEMM, m97 structure ----------------
// C[M,N] = A[M,K] * W[N,K]^T, 128x128 tile, BK=64, 4 waves 2x2, each wave
// 64x64 via 4x4 16x16x32 MFMAs. Staging via global_load_lds width=16 into
// LINEAR LDS (required). Output column n maps to matrix t=n>>9 (QKV fusion).
#define BM 128
#define BN 128
#define BK 64

struct GemmZ {
  const _Float16* A;
  const _Float16* W;
  _Float16* C0;
  _Float16* C1;
  _Float16* C2;
  long colOff;
  int K;
  int lda;
  int ostride;
  int colBase;
  int nblk;  // N/BN
  int cpx;   // gridDim.x/8 (gridDim.x % 8 == 0 -> bijective swizzle)
};
struct GemmP { GemmZ z[NSEG]; };

__device__ __forceinline__ void gld16(const _Float16* g, _Float16* l) {
  __builtin_amdgcn_global_load_lds(
      (__attribute__((address_space(1))) unsigned int*)g,
      (__attribute__((address_space(3))) unsigned int*)l, 16, 0, 0);
}

__launch_bounds__(256, 3)
__global__ void k_gemm(GemmP p) {
  __shared__ _Float16 As[BM * BK];
  __shared__ _Float16 Bs[BN * BK];
  GemmZ g = p.z[blockIdx.z];
  // XCD-chunk swizzle: consecutive hw blocks (round-robin XCDs) -> contiguous
  // logical chunks per XCD; the nblk n-blocks of one m-panel become L2-local.
  const int bid = blockIdx.x;
  const int swz = (bid & 7) * g.cpx + (bid >> 3);
  const int mb = swz / g.nblk;
  const int nb = swz - mb * g.nblk;
  const int m0 = mb * BM, n0 = nb * BN;
  const int tid = threadIdx.x;
  const int lane = tid & 63;
  const int wid = tid >> 6;
  const int wm = (wid >> 1) * 64;
  const int wn = (wid & 1) * 64;
  const int lr = lane & 15, lq = lane >> 4;
  const _Float16* Ab = g.A + (long)m0 * g.lda + g.colOff;
  const _Float16* Wb = g.W + (long)n0 * g.K;
  floatx4 acc[4][4] = {};

  for (int k0 = 0; k0 < g.K; k0 += BK) {
    // 1024 16B-chunks per tile; thread t, iter r handles chunk c=r*256+t.
    // LDS dest = wave-uniform base + lane*16 as gld_lds requires.
    for (int r = 0; r < 4; ++r) {
      int c = r * 256 + tid;
      gld16(Ab + (long)(c >> 3) * g.lda + k0 + (c & 7) * 8, As + c * 8);
    }
    for (int r = 0; r < 4; ++r) {
      int c = r * 256 + tid;
      gld16(Wb + (long)(c >> 3) * g.K + k0 + (c & 7) * 8, Bs + c * 8);
    }
    __syncthreads();  // compiler emits vmcnt(0) drain here (m97 structure)
    for (int kk = 0; kk < BK; kk += 32) {
      half8 af[4], bf[4];
      for (int mt = 0; mt < 4; ++mt)
        af[mt] = *(const half8*)(As + (wm + mt * 16 + lr) * BK + kk + lq * 8);
      for (int nt = 0; nt < 4; ++nt)
        bf[nt] = *(const half8*)(Bs + (wn + nt * 16 + lr) * BK + kk + lq * 8);
      for (int mt = 0; mt < 4; ++mt)
        for (int nt = 0; nt < 4; ++nt)
          acc[mt][nt] = __builtin_amdgcn_mfma_f32_16x16x32_f16(af[mt], bf[nt], acc[mt][nt], 0, 0, 0);
    }
    __syncthreads();
  }
  // C/D layout: col=lane&15, row=(lane>>4)*4+reg (verified in prior kernel)
  const int t = n0 >> 9;  // block's 128-col range never crosses a 512 boundary
  _Float16* Cb = (t == 0) ? g.C0 : (t == 1) ? g.C1 : g.C2;
  const int cb = g.colBase + (n0 & 511);
  for (int mt = 0; mt < 4; ++mt)
    for (int nt = 0; nt < 4; ++nt)
      for (int r = 0; r < 4; ++r) {
        int mg = m0 + wm + mt * 16 + lq * 4 + r;
        int nc = cb + wn + nt * 16 + lr;
        Cb[(long)mg * g.ostride + nc] = (_Float16)acc[mt][nt][r];
      }
}

// ---------------- fused attention (per batch row) ----------------
// 1 wave per local row; block = 2 waves. All LDS rows are 1024B; natural reads
// would be 128B-stride same-bank. XOR swizzle: byte bits[4:6] ^= f(bits>=7),
// applied identically at stage-write and every read.
#define AWPB 2
__device__ __forceinline__ int swz16(int b) {
  return b ^ ((((b >> 7) ^ (b >> 10)) & 7) << 4);
}

__launch_bounds__(128)
__global__ void k_att(const _Float16* Qh, const _Float16* Kh, const _Float16* Vh,
                      _Float16* Oh, void* dout, const int* flag, long b0) {
  __shared__ __align__(16) _Float16 qs[AWPB][3072];
  __shared__ __align__(16) _Float16 ks[AWPB][3072];
  __shared__ __align__(16) _Float16 vs[AWPB][3072];
  __shared__ float ss[AWPB][288];
  const int lane = threadIdx.x & 63;
  const int wv = threadIdx.x >> 6;
  const long b = (long)blockIdx.x * AWPB + wv;  // local row in this half
  const long bg = b + b0;                       // global row (for dout)
  const int isbf = flag[0];
  char* qb = (char*)qs[wv];
  char* kb = (char*)ks[wv];
  char* vb = (char*)vs[wv];
  {
    const uint4* qsrc = (const uint4*)(Qh + b * 3072);
    const uint4* ksrc = (const uint4*)(Kh + b * 3072);
    const uint4* vsrc = (const uint4*)(Vh + b * 3072);
    for (int t = 0; t < 6; ++t) {
      int i = lane + 64 * t;         // 384 uint4 per buffer
      int off = swz16(i * 16);       // permutation within each 128B row block
      *(uint4*)(qb + off) = qsrc[i];
      *(uint4*)(kb + off) = ksrc[i];
      *(uint4*)(vb + off) = vsrc[i];
    }
  }
  __syncthreads();
  // logits s[h,i,j] = q[i,h*64:].k[j,h*64:] / 8  — b128 LDS reads
  for (int idx = lane; idx < 288; idx += 64) {
    int h = idx / 36, rem = idx % 36, i = rem / 6, j = rem % 6;
    int qoff = swz16(i * 1024 + h * 128);
    int koff = swz16(j * 1024 + h * 128);
    float a = 0.f;
    for (int c8 = 0; c8 < 8; ++c8) {
      half8 qv = *(const half8*)(qb + (qoff ^ (c8 << 4)));
      half8 kv = *(const half8*)(kb + (koff ^ (c8 << 4)));
      for (int e = 0; e < 8; ++e) a += (float)qv[e] * (float)kv[e];
    }
    ss[wv][idx] = a * 0.125f;
  }
  __syncthreads();
  // per (h,i) row: L2-normalize (global-min division cancels) + softmax
  if (lane < 48) {
    float* sp = ss[wv] + lane * 6;
    float n2 = 0.f;
    for (int j = 0; j < 6; ++j) n2 += sp[j] * sp[j];
    float inv = 1.0f / fmaxf(sqrtf(n2), 1e-12f);
    float mx = -1e30f;
    for (int j = 0; j < 6; ++j) mx = fmaxf(mx, sp[j] * inv);
    float sum = 0.f;
    for (int j = 0; j < 6; ++j) {
      float e = expf(sp[j] * inv - mx);
      sp[j] = e;
      sum += e;
    }
    float rcp = 1.0f / sum;
    for (int j = 0; j < 6; ++j) sp[j] *= rcp;
  }
  __syncthreads();
  for (int idx = lane; idx < 288; idx += 64)
    st_any(dout, OUT0_ELEMS + bg * 288 + idx, ss[wv][idx], isbf);
  // o[i, h*64+d] = sum_j attn[h,i,j] * v[j, h*64+d] — half8 chunks
  for (int t = 0; t < 6; ++t) {
    int ci = lane + 64 * t;       // chunk of 8 halfs, 0..383
    int i = ci >> 6;              // row (64 chunks per 512-half row)
    int cbyt = (ci & 63) * 16;    // byte col within row
    int h = cbyt >> 7;
    const float* ap = ss[wv] + h * 36 + i * 6;
    float o[8] = {0.f, 0.f, 0.f, 0.f, 0.f, 0.f, 0.f, 0.f};
    for (int j = 0; j < 6; ++j) {
      half8 v8 = *(const half8*)(vb + swz16(j * 1024 + cbyt));
      float aj = ap[j];
      for (int e = 0; e < 8; ++e) o[e] += aj * (float)v8[e];
    }
    half8 r8;
    for (int e = 0; e < 8; ++e) r8[e] = (_Float16)o[e];
    *(half8*)(Oh + b * 3072 + (long)ci * 8) = r8;
  }
}

// ---------------- bias + residual + LayerNorm ----------------
__launch_bounds__(256)
__global__ void k_epi(const _Float16* Yh, const _Float16* Vh, const void* fcb,
                      const void* lng, const void* lnb, void* dout,
                      const int* flag, long rof) {
  const int lane = threadIdx.x & 63;
  const int wv = threadIdx.x >> 6;
  const long r = (long)blockIdx.x * 4 + wv;  // local row in this half
  const int isbf = flag[0];
  const int c0 = lane * 8;
  half8 y8 = *(const half8*)(Yh + r * 512 + c0);
  half8 v8 = *(const half8*)(Vh + r * 512 + c0);
  float x[8];
  float s = 0.f, s2 = 0.f;
  for (int j = 0; j < 8; ++j) {
    float v = (float)y8[j] + (float)v8[j] + ld_any(fcb, c0 + j, isbf);
    x[j] = v;
    s += v;
    s2 += v * v;
  }
  for (int off = 32; off > 0; off >>= 1) {
    s += __shfl_xor(s, off);
    s2 += __shfl_xor(s2, off);
  }
  float mu = s * (1.0f / 512.0f);
  float var = s2 * (1.0f / 512.0f) - mu * mu;
  float rs = 1.0f / sqrtf(var + 1e-6f);
  float ov[8];
  for (int j = 0; j < 8; ++j)
    ov[j] = (x[j] - mu) * rs * ld_any(lng, c0 + j, isbf) + ld_any(lnb, c0 + j, isbf);
  const long rg = r + rof;
  if (isbf) {
    uint4 pk;
    pk.x = f_to_bf(ov[0]) | ((unsigned int)f_to_bf(ov[1]) << 16);
    pk.y = f_to_bf(ov[2]) | ((unsigned int)f_to_bf(ov[3]) << 16);
    pk.z = f_to_bf(ov[4]) | ((unsigned int)f_to_bf(ov[5]) << 16);
    pk.w = f_to_bf(ov[6]) | ((unsigned int)f_to_bf(ov[7]) << 16);
    *(uint4*)((unsigned short*)dout + rg * 512 + c0) = pk;
  } else {
    float* dp = (float*)dout + rg * 512 + c0;
    float4 f0, f1;
    f0.x = ov[0]; f0.y = ov[1]; f0.z = ov[2]; f0.w = ov[3];
    f1.x = ov[4]; f1.y = ov[5]; f1.z = ov[6]; f1.w = ov[7];
    *(float4*)dp = f0;
    *((float4*)dp + 1) = f1;
  }
}

// ---------------- host launcher ----------------
extern "C" void kernel_launch(void* const* d_in, const int* in_sizes, int n_in,
                              void* d_out, int out_size, void* d_ws, size_t ws_size,
                              hipStream_t stream) {
  static const int dims[NSEG] = {2048, 1024, 512, 1536, 768, 256};
  static const int offs[NSEG] = {0, 2048, 3072, 3584, 5120, 5888};
  char* ws = (char*)d_ws;
  int* flag = (int*)ws;
  _Float16* Wh  = (_Float16*)(ws + 256);
  _Float16* A16 = (_Float16*)(ws + 19398912L);   // 8192 x 6144 fp16
  _Float16* Qh  = (_Float16*)(ws + 120062208L);  // 8192 x 3072 fp16
  _Float16* Kh  = (_Float16*)(ws + 170393856L);
  _Float16* Vh  = (_Float16*)(ws + 220725504L);  // ends 271057152 (< 321388800)
  _Float16* Oh  = A16;  // A16 dead after proj GEMM of its half
  _Float16* Yh  = Qh;   // Qh dead after k_att of its half

  k_detect<<<1, 256, 0, stream>>>((const unsigned short*)d_in[0], flag);

  PrepArgs pa;
  int c = 0;
  for (int a = 0; a < 19; ++a) {
    pa.src[a] = d_in[1 + a];  // wq0,wk0,wv0,...,wv5, fc_w
    pa.cs[a] = c;
    c += (a < 18) ? 512 * dims[a / 3] : 512 * 512;
  }
  pa.cs[19] = c;  // 9699328 total elems
  k_prep<<<(c + 255) / 256, 256, 0, stream>>>(pa, Wh, flag, c);

  // 6 fused QKV GEMMs per half: N=1536 per segment (wq|wk|wv contiguous in Wh)
  GemmP g1;
  for (int s = 0; s < NSEG; ++s) {
    g1.z[s].A = A16;
    g1.z[s].W = Wh + pa.cs[3 * s];
    g1.z[s].C0 = Qh;
    g1.z[s].C1 = Kh;
    g1.z[s].C2 = Vh;
    g1.z[s].colOff = offs[s];
    g1.z[s].K = dims[s];
    g1.z[s].lda = LDA;
    g1.z[s].ostride = 3072;
    g1.z[s].colBase = s * 512;
    g1.z[s].nblk = 1536 / BN;                 // 12
    g1.z[s].cpx = (BS_HALF / BM) * 12 / 8;    // 768/8 = 96
  }
  // fc GEMM per half: (49152 x 512) = Oh @ fc_w^T
  GemmP g2;
  g2.z[0].A = Oh;
  g2.z[0].W = Wh + pa.cs[18];
  g2.z[0].C0 = Yh;
  g2.z[0].C1 = Yh;
  g2.z[0].C2 = Yh;
  g2.z[0].colOff = 0;
  g2.z[0].K = 512;
  g2.z[0].lda = 512;
  g2.z[0].ostride = 512;
  g2.z[0].colBase = 0;
  g2.z[0].nblk = 512 / BN;                    // 4
  g2.z[0].cpx = (BS_HALF * NSEG / BM) * 4 / 8;  // 1536/8 = 192
  for (int z = 1; z < NSEG; ++z) g2.z[z] = g2.z[0];

  for (int h = 0; h < 2; ++h) {
    const long elem0 = (long)h * BS_HALF * LDA;
    // input half -> fp16 (8192*6144/8 = 6291456 chunks)
    k_cvtA<<<2048, 256, 0, stream>>>(d_in[0], A16, flag, elem0, 6291456L);
    k_gemm<<<dim3((BS_HALF / BM) * 12, 1, NSEG), 256, 0, stream>>>(g1);
    k_att<<<BS_HALF / AWPB, 64 * AWPB, 0, stream>>>(Qh, Kh, Vh, Oh, d_out, flag,
                                                    (long)h * BS_HALF);
    k_gemm<<<dim3((BS_HALF * NSEG / BM) * 4, 1, 1), 256, 0, stream>>>(g2);
    k_epi<<<BS_HALF * NSEG / 4, 256, 0, stream>>>(Yh, Vh, d_in[20], d_in[21],
                                                  d_in[22], d_out, flag,
                                                  (long)h * BS_HALF * NSEG);
  }
}